// Round 7
// baseline (152.758 us; speedup 1.0000x reference)
//
#include <hip/hip_runtime.h>
#include <stdint.h>

// Grossberg shunting ODE, 127 Euler steps, BATCH=32768, N=17.
// R3 structure: 4 lanes/item, W f16-packed (90 u32/lane), dot2 matvec,
// __shfl(width=4) state broadcast (DS pipe, off the saturated VALU).
// R7: per-iteration asm pins on W + constants — redefines them in arch
// VGPRs every step, so the allocator cannot park them in AGPRs and pay
// v_accvgpr_read per use (the suspected 2x dynamic-instruction bloat).

typedef _Float16 h2 __attribute__((ext_vector_type(2)));
typedef __fp16 h2raw __attribute__((ext_vector_type(2)));
typedef float f4a __attribute__((ext_vector_type(4), aligned(4)));

static constexpr int BATCH = 32768;
static constexpr int NN = 17;
static constexpr int TT = 128;

#define PIN(x) asm volatile("" : "+v"(x))

__device__ __forceinline__ uint32_t pk(float a, float b) {
    h2raw h = __builtin_amdgcn_cvt_pkrtz(a, b);
    return __builtin_bit_cast(uint32_t, h);
}
__device__ __forceinline__ float dot2(uint32_t a, uint32_t b, float c) {
    return __builtin_amdgcn_fdot2(__builtin_bit_cast(h2, a),
                                  __builtin_bit_cast(h2, b), c, false);
}
__device__ __forceinline__ float lo16(uint32_t u) {
    h2 h = __builtin_bit_cast(h2, u); return (float)h.x;
}
__device__ __forceinline__ float hi16(uint32_t u) {
    h2 h = __builtin_bit_cast(h2, u); return (float)h.y;
}

__global__ __launch_bounds__(256)
__attribute__((amdgpu_waves_per_eu(2, 2)))
void hotco_kernel(
    const float* __restrict__ state0,
    const float* __restrict__ Wpos,
    const float* __restrict__ Wneg,
    const float* __restrict__ feas,
    const float* __restrict__ P,
    const float* __restrict__ t_eval,
    float* __restrict__ out)
{
    const int tid = blockIdx.x * blockDim.x + threadIdx.x;
    const int lane4 = tid & 3;
    const int b = tid >> 2;

    // lane0: rows 0-4 (needs), lane1: 5-8 (needs), lane2: 9-12 (acts), lane3: 13-16 (vals)
    const int base = (lane4 == 0) ? 0 : (4 * lane4 + 1);
    const int nrows = (lane4 == 0) ? 5 : 4;

    // pair grouping: (0,1)(2,3)(4,-)(5,6)(7,8)(9,10)(11,12)(13,14)(15,16)
    constexpr int pA[9] = {0, 2, 4, 5, 7, 9, 11, 13, 15};
    constexpr int pB[9] = {1, 3, -1, 6, 8, 10, 12, 14, 16};

    // ---- W into registers, packed f16 pairs (90 u32 per lane) ----
    uint32_t w[5][9], wn[5][9];
    {
        const float* wpb = Wpos + (size_t)b * (NN * NN);
        const float* wnb = Wneg + (size_t)b * (NN * NN);
#pragma unroll
        for (int t = 0; t < 5; ++t) {
            if (t < nrows) {
                const float* rp = wpb + (base + t) * NN;
                const float* rn = wnb + (base + t) * NN;
#pragma unroll
                for (int c = 0; c < 9; ++c) {
                    float a2 = (pB[c] < 0) ? 0.f : rp[pB[c]];
                    float b2 = (pB[c] < 0) ? 0.f : rn[pB[c]];
                    w[t][c]  = pk(rp[pA[c]], a2);
                    wn[t][c] = pk(rn[pA[c]], b2);
                }
            } else {
#pragma unroll
                for (int c = 0; c < 9; ++c) { w[t][c] = 0u; wn[t][c] = 0u; }
            }
        }
    }

    // ---- per-lane-class constants ----
    float cA[5], cB[5], pdv[4];
#pragma unroll
    for (int t = 0; t < 5; ++t) { cA[t] = 0.f; cB[t] = 0.f; }
#pragma unroll
    for (int t = 0; t < 4; ++t) pdv[t] = 0.f;
    if (lane4 < 2) {
#pragma unroll
        for (int t = 0; t < 5; ++t) {
            if (t < nrows) {
                float pv = P[(size_t)b * NN + base + t];
                cA[t] = fmaxf(pv, 0.f);
                cB[t] = fmaxf(-pv, 0.f);
            }
        }
    } else if (lane4 == 2) {
#pragma unroll
        for (int t = 0; t < 4; ++t) {
            cA[t] = feas[(size_t)b * 4 + t];
            cB[t] = P[(size_t)b * NN + 13 + t];
        }
    } else {
#pragma unroll
        for (int t = 0; t < 4; ++t)
            pdv[t] = P[(size_t)b * NN + 13 + t];
    }

    // ---- initial replicated packed state + own f32 slots ----
    uint32_t s2[9];
    {
        const float* sb = state0 + (size_t)b * NN;
        float st[17];
#pragma unroll
        for (int j = 0; j < NN; ++j) st[j] = sb[j];
        s2[0] = pk(st[0], st[1]);   s2[1] = pk(st[2], st[3]);
        s2[2] = pk(st[4], 0.f);     s2[3] = pk(st[5], st[6]);
        s2[4] = pk(st[7], st[8]);   s2[5] = pk(st[9], st[10]);
        s2[6] = pk(st[11], st[12]); s2[7] = pk(st[13], st[14]);
        s2[8] = pk(st[15], st[16]);
    }
    float sOwn[5];
#pragma unroll
    for (int t = 0; t < 5; ++t)
        sOwn[t] = (t < nrows) ? state0[(size_t)b * NN + base + t] : 0.f;

    const float lo = (lane4 == 3) ? -1.f : 0.f;
    const float dtv = t_eval[1] - t_eval[0];
    const float k1 = dtv * 1.25f;                 // dt / TAU
    const float C  = -1.0820212806667226f;        // -0.75 * log2(e)

    // ---- write step 0 ----
    {
        float* op = out + (size_t)b * NN + base;
        f4a v0; v0.x = sOwn[0]; v0.y = sOwn[1]; v0.z = sOwn[2]; v0.w = sOwn[3];
        *(f4a*)op = v0;
        if (nrows == 5) op[4] = sOwn[4];
    }
    float* outp = out + (size_t)BATCH * NN + (size_t)b * NN + base;

#pragma unroll 1
    for (int st = 1; st < TT; ++st) {
        // ---- per-iteration pins: force W + constants into arch VGPRs.
        // "+v" redefines the value each step, so an AGPR master copy
        // cannot survive — no v_accvgpr_read in the hot loop. Emits 0 instrs.
#pragma unroll
        for (int t = 0; t < 5; ++t)
#pragma unroll
            for (int c = 0; c < 9; ++c) { PIN(w[t][c]); PIN(wn[t][c]); }
#pragma unroll
        for (int t = 0; t < 5; ++t) { PIN(cA[t]); PIN(cB[t]); }
#pragma unroll
        for (int t = 0; t < 4; ++t) PIN(pdv[t]);

        // ---- matvec: 2 x (5 rows x 9 dot2), uniform relu ----
        float E5[5], I5[5];
#pragma unroll
        for (int t = 0; t < 5; ++t) {
            float ae = 0.f, ai = 0.f;
#pragma unroll
            for (int c = 0; c < 9; ++c) {
                ae = dot2(w[t][c], s2[c], ae);
                ai = dot2(wn[t][c], s2[c], ai);
            }
            E5[t] = fmaxf(ae, 0.f);   // relu(g*x) = g*relu(x), g>0
            I5[t] = fmaxf(ai, 0.f);
        }

        // ---- class transform (lane2 masked; others cheap adds) ----
        if (lane4 == 2) {
            const float sum_acts = sOwn[0] + sOwn[1] + sOwn[2] + sOwn[3];
            const float v13[4] = { lo16(s2[7]), hi16(s2[7]), lo16(s2[8]), hi16(s2[8]) };
#pragma unroll
            for (int t = 0; t < 4; ++t) {
                float v  = v13[t] + cB[t];
                float e1 = __builtin_amdgcn_exp2f(C * v);              // e^(-0.75 v)
                float ge = __builtin_amdgcn_rcpf(fmaf(e1, e1, 1.f));   // sigmoid(1.5v)
                float gi = e1 * __builtin_amdgcn_rcpf(1.f + e1);       // sigmoid(-0.75v)
                E5[t] = ge * E5[t] * cA[t];
                float os  = sum_acts - sOwn[t];
                float lat = fmaf(-0.9f, __builtin_amdgcn_rcpf(0.3f + os), 3.0f);
                I5[t] = fmaf(gi, I5[t], lat);
            }
            E5[4] = 0.f; I5[4] = 0.f;
        } else {
#pragma unroll
            for (int t = 0; t < 5; ++t) { E5[t] += cA[t]; I5[t] += cB[t]; }
        }

        // ---- shunting update + clip ----
#pragma unroll
        for (int t = 0; t < 5; ++t) {
            float s  = sOwn[t];
            float d0 = fmaf(-0.15f, s, (t < 4) ? pdv[t] : 0.f);  // pdv==0 off lane3
            float d1 = fmaf(1.f - s, E5[t], d0);
            float d2 = fmaf(-(0.1f + s), I5[t], d1);
            float raw = fmaf(k1, d2, s);
            sOwn[t] = fminf(fmaxf(raw, lo), 1.f);
        }

        // ---- pack own block, broadcast via __shfl (DS pipe) ----
        uint32_t p0 = pk(sOwn[0], sOwn[1]);
        uint32_t p1 = pk(sOwn[2], sOwn[3]);
        uint32_t p2 = pk(sOwn[4], 0.f);
        s2[0] = (uint32_t)__shfl((int)p0, 0, 4);
        s2[1] = (uint32_t)__shfl((int)p1, 0, 4);
        s2[2] = (uint32_t)__shfl((int)p2, 0, 4);
        s2[3] = (uint32_t)__shfl((int)p0, 1, 4);
        s2[4] = (uint32_t)__shfl((int)p1, 1, 4);
        s2[5] = (uint32_t)__shfl((int)p0, 2, 4);
        s2[6] = (uint32_t)__shfl((int)p1, 2, 4);
        s2[7] = (uint32_t)__shfl((int)p0, 3, 4);
        s2[8] = (uint32_t)__shfl((int)p1, 3, 4);

        // ---- store (float4 + lane0 scalar) ----
        {
            f4a v0; v0.x = sOwn[0]; v0.y = sOwn[1]; v0.z = sOwn[2]; v0.w = sOwn[3];
            *(f4a*)outp = v0;
            if (nrows == 5) outp[4] = sOwn[4];
        }
        outp += (size_t)BATCH * NN;
    }
}

extern "C" void kernel_launch(void* const* d_in, const int* in_sizes, int n_in,
                              void* d_out, int out_size, void* d_ws, size_t ws_size,
                              hipStream_t stream) {
    const float* state0 = (const float*)d_in[0];
    const float* Wpos   = (const float*)d_in[1];
    const float* Wneg   = (const float*)d_in[2];
    const float* feasv  = (const float*)d_in[3];
    const float* P      = (const float*)d_in[4];
    const float* t_eval = (const float*)d_in[5];
    float* out = (float*)d_out;

    dim3 grid(BATCH * 4 / 256), block(256);
    hipLaunchKernelGGL(hotco_kernel, grid, block, 0, stream,
                       state0, Wpos, Wneg, feasv, P, t_eval, out);
}

// Round 8
// 148.696 us; speedup vs baseline: 1.0273x; 1.0273x over previous
//
#include <hip/hip_runtime.h>
#include <stdint.h>

// Grossberg shunting ODE, 127 Euler steps, BATCH=32768, N=17.
// R3 structure: 4 lanes/item, W f16-packed (90 u32/lane), dot2 matvec.
// R8: raw ds_swizzle immediate quad-broadcasts (1 DS inst, no addr VALU),
// no pins, float4 stores. Everything else identical to R3 (best: 147.6us).

typedef _Float16 h2 __attribute__((ext_vector_type(2)));
typedef __fp16 h2raw __attribute__((ext_vector_type(2)));
typedef float f4a __attribute__((ext_vector_type(4), aligned(4)));

static constexpr int BATCH = 32768;
static constexpr int NN = 17;
static constexpr int TT = 128;

__device__ __forceinline__ uint32_t pk(float a, float b) {
    h2raw h = __builtin_amdgcn_cvt_pkrtz(a, b);
    return __builtin_bit_cast(uint32_t, h);
}
__device__ __forceinline__ float dot2(uint32_t a, uint32_t b, float c) {
    return __builtin_amdgcn_fdot2(__builtin_bit_cast(h2, a),
                                  __builtin_bit_cast(h2, b), c, false);
}
__device__ __forceinline__ float lo16(uint32_t u) {
    h2 h = __builtin_bit_cast(h2, u); return (float)h.x;
}
__device__ __forceinline__ float hi16(uint32_t u) {
    h2 h = __builtin_bit_cast(h2, u); return (float)h.y;
}
// ds_swizzle BitMode: src_lane = ((lane & and) | or) ^ xor.
// Quad broadcast of quad-lane K: and=0x1C, or=K, xor=0 -> (K<<5)|0x1C.
template <int K>
__device__ __forceinline__ uint32_t qswz(uint32_t v) {
    return (uint32_t)__builtin_amdgcn_ds_swizzle((int)v, (K << 5) | 0x1C);
}

__global__ __launch_bounds__(256, 2) void hotco_kernel(
    const float* __restrict__ state0,
    const float* __restrict__ Wpos,
    const float* __restrict__ Wneg,
    const float* __restrict__ feas,
    const float* __restrict__ P,
    const float* __restrict__ t_eval,
    float* __restrict__ out)
{
    const int tid = blockIdx.x * blockDim.x + threadIdx.x;
    const int lane4 = tid & 3;
    const int b = tid >> 2;
    if (b >= BATCH) return;

    // lane0: rows 0-4 (needs), lane1: 5-8 (needs), lane2: 9-12 (acts), lane3: 13-16 (vals)
    const int base = (lane4 == 0) ? 0 : (4 * lane4 + 1);
    const int nrows = (lane4 == 0) ? 5 : 4;

    // pair grouping: (0,1)(2,3)(4,-)(5,6)(7,8)(9,10)(11,12)(13,14)(15,16)
    constexpr int pA[9] = {0, 2, 4, 5, 7, 9, 11, 13, 15};
    constexpr int pB[9] = {1, 3, -1, 6, 8, 10, 12, 14, 16};

    // ---- W into registers, packed f16 pairs (90 u32 per lane) ----
    uint32_t w[5][9], wn[5][9];
    {
        const float* wpb = Wpos + (size_t)b * (NN * NN);
        const float* wnb = Wneg + (size_t)b * (NN * NN);
#pragma unroll
        for (int t = 0; t < 5; ++t) {
            if (t < nrows) {
                const float* rp = wpb + (base + t) * NN;
                const float* rn = wnb + (base + t) * NN;
#pragma unroll
                for (int c = 0; c < 9; ++c) {
                    float a2 = (pB[c] < 0) ? 0.f : rp[pB[c]];
                    float b2 = (pB[c] < 0) ? 0.f : rn[pB[c]];
                    w[t][c]  = pk(rp[pA[c]], a2);
                    wn[t][c] = pk(rn[pA[c]], b2);
                }
            } else {
#pragma unroll
                for (int c = 0; c < 9; ++c) { w[t][c] = 0u; wn[t][c] = 0u; }
            }
        }
    }

    // ---- per-lane-class constants ----
    float cA[5], cB[5], pdv[4];
#pragma unroll
    for (int t = 0; t < 5; ++t) { cA[t] = 0.f; cB[t] = 0.f; }
#pragma unroll
    for (int t = 0; t < 4; ++t) pdv[t] = 0.f;
    if (lane4 < 2) {
#pragma unroll
        for (int t = 0; t < 5; ++t) {
            if (t < nrows) {
                float pv = P[(size_t)b * NN + base + t];
                cA[t] = fmaxf(pv, 0.f);
                cB[t] = fmaxf(-pv, 0.f);
            }
        }
    } else if (lane4 == 2) {
#pragma unroll
        for (int t = 0; t < 4; ++t) {
            cA[t] = feas[(size_t)b * 4 + t];
            cB[t] = P[(size_t)b * NN + 13 + t];
        }
    } else {
#pragma unroll
        for (int t = 0; t < 4; ++t)
            pdv[t] = P[(size_t)b * NN + 13 + t];
    }

    // ---- initial replicated packed state + own f32 slots ----
    uint32_t s2[9];
    {
        const float* sb = state0 + (size_t)b * NN;
        float st[17];
#pragma unroll
        for (int j = 0; j < NN; ++j) st[j] = sb[j];
        s2[0] = pk(st[0], st[1]);   s2[1] = pk(st[2], st[3]);
        s2[2] = pk(st[4], 0.f);     s2[3] = pk(st[5], st[6]);
        s2[4] = pk(st[7], st[8]);   s2[5] = pk(st[9], st[10]);
        s2[6] = pk(st[11], st[12]); s2[7] = pk(st[13], st[14]);
        s2[8] = pk(st[15], st[16]);
    }
    float sOwn[5];
#pragma unroll
    for (int t = 0; t < 5; ++t)
        sOwn[t] = (t < nrows) ? state0[(size_t)b * NN + base + t] : 0.f;

    const float lo = (lane4 == 3) ? -1.f : 0.f;
    const float dtv = t_eval[1] - t_eval[0];
    const float k1 = dtv * 1.25f;                 // dt / TAU
    const float C  = -1.0820212806667226f;        // -0.75 * log2(e)

    // ---- write step 0 ----
    {
        float* op = out + (size_t)b * NN + base;
        f4a v0; v0.x = sOwn[0]; v0.y = sOwn[1]; v0.z = sOwn[2]; v0.w = sOwn[3];
        *(f4a*)op = v0;
        if (nrows == 5) op[4] = sOwn[4];
    }
    float* outp = out + (size_t)BATCH * NN + (size_t)b * NN + base;

#pragma unroll 1
    for (int st = 1; st < TT; ++st) {
        // ---- matvec: 2 x (5 rows x 9 dot2), uniform relu ----
        float E5[5], I5[5];
#pragma unroll
        for (int t = 0; t < 5; ++t) {
            float ae = 0.f, ai = 0.f;
#pragma unroll
            for (int c = 0; c < 9; ++c) {
                ae = dot2(w[t][c], s2[c], ae);
                ai = dot2(wn[t][c], s2[c], ai);
            }
            E5[t] = fmaxf(ae, 0.f);   // relu(g*x) = g*relu(x), g>0
            I5[t] = fmaxf(ai, 0.f);
        }

        // ---- class transform (lane2 masked; others cheap adds) ----
        if (lane4 == 2) {
            const float sum_acts = sOwn[0] + sOwn[1] + sOwn[2] + sOwn[3];
            const float v13[4] = { lo16(s2[7]), hi16(s2[7]), lo16(s2[8]), hi16(s2[8]) };
#pragma unroll
            for (int t = 0; t < 4; ++t) {
                float v  = v13[t] + cB[t];
                float e1 = __builtin_amdgcn_exp2f(C * v);              // e^(-0.75 v)
                float ge = __builtin_amdgcn_rcpf(fmaf(e1, e1, 1.f));   // sigmoid(1.5v)
                float gi = e1 * __builtin_amdgcn_rcpf(1.f + e1);       // sigmoid(-0.75v)
                E5[t] = ge * E5[t] * cA[t];
                float os  = sum_acts - sOwn[t];
                float lat = fmaf(-0.9f, __builtin_amdgcn_rcpf(0.3f + os), 3.0f);
                I5[t] = fmaf(gi, I5[t], lat);
            }
            E5[4] = 0.f; I5[4] = 0.f;
        } else {
#pragma unroll
            for (int t = 0; t < 5; ++t) { E5[t] += cA[t]; I5[t] += cB[t]; }
        }

        // ---- shunting update + clip ----
#pragma unroll
        for (int t = 0; t < 5; ++t) {
            float s  = sOwn[t];
            float d0 = fmaf(-0.15f, s, (t < 4) ? pdv[t] : 0.f);  // pdv==0 off lane3
            float d1 = fmaf(1.f - s, E5[t], d0);
            float d2 = fmaf(-(0.1f + s), I5[t], d1);
            float raw = fmaf(k1, d2, s);
            sOwn[t] = fminf(fmaxf(raw, lo), 1.f);
        }

        // ---- pack own block, quad-broadcast via ds_swizzle imm ----
        uint32_t p0 = pk(sOwn[0], sOwn[1]);
        uint32_t p1 = pk(sOwn[2], sOwn[3]);
        uint32_t p2 = pk(sOwn[4], 0.f);
        s2[0] = qswz<0>(p0); s2[1] = qswz<0>(p1); s2[2] = qswz<0>(p2);
        s2[3] = qswz<1>(p0); s2[4] = qswz<1>(p1);
        s2[5] = qswz<2>(p0); s2[6] = qswz<2>(p1);
        s2[7] = qswz<3>(p0); s2[8] = qswz<3>(p1);

        // ---- store (float4 + lane0 scalar) ----
        {
            f4a v0; v0.x = sOwn[0]; v0.y = sOwn[1]; v0.z = sOwn[2]; v0.w = sOwn[3];
            *(f4a*)outp = v0;
            if (nrows == 5) outp[4] = sOwn[4];
        }
        outp += (size_t)BATCH * NN;
    }
}

extern "C" void kernel_launch(void* const* d_in, const int* in_sizes, int n_in,
                              void* d_out, int out_size, void* d_ws, size_t ws_size,
                              hipStream_t stream) {
    const float* state0 = (const float*)d_in[0];
    const float* Wpos   = (const float*)d_in[1];
    const float* Wneg   = (const float*)d_in[2];
    const float* feasv  = (const float*)d_in[3];
    const float* P      = (const float*)d_in[4];
    const float* t_eval = (const float*)d_in[5];
    float* out = (float*)d_out;

    dim3 grid(BATCH * 4 / 256), block(256);
    hipLaunchKernelGGL(hotco_kernel, grid, block, 0, stream,
                       state0, Wpos, Wneg, feasv, P, t_eval, out);
}